// Round 6
// baseline (5397.555 us; speedup 1.0000x reference)
//
#include <hip/hip_runtime.h>
#include <hip/hip_bf16.h>

typedef float f32x4 __attribute__((ext_vector_type(4)));

#define N_NODES 20000
#define NGENES  2000
#define NEDGE   640000
#define EMB     128
#define ED      32
#define PD      64
#define OUTD    16
#define KEMB    2000

// ---------------- max(src) reduction ----------------
__global__ __launch_bounds__(256) void k_srcmax(const int* __restrict__ src,
                                                int* __restrict__ out) {
    __shared__ int sm[256];
    int i = blockIdx.x * 256 + threadIdx.x;
    sm[threadIdx.x] = (i < NEDGE) ? src[i] : 0;
    __syncthreads();
    for (int s = 128; s > 0; s >>= 1) {
        if (threadIdx.x < s) sm[threadIdx.x] = max(sm[threadIdx.x], sm[threadIdx.x + s]);
        __syncthreads();
    }
    if (threadIdx.x == 0) atomicMax(out, sm[0]);
}

// ---------------- embedding GEMM f32: h = x @ W_emb + b ----------------
// 64x64 tile, 256 threads (16x16), 4x4 per thread, K staged 16 deep.
__global__ __launch_bounds__(256) void k_emb_f32(const float* __restrict__ x,
                                                 const float* __restrict__ W,   // [2000][128]
                                                 const float* __restrict__ bias,
                                                 float* __restrict__ h) {
    __shared__ float As[64 * 17];
    __shared__ float Bs[16 * 64];
    int tid = threadIdx.x;
    int mt = blockIdx.x >> 1, nt = blockIdx.x & 1;
    int row0 = mt * 64, n0 = nt * 64;
    int tx = tid & 15, ty = tid >> 4;
    float acc[4][4] = {};
    int ar = tid >> 2, ac = (tid & 3) * 4;   // A stage: row, k-chunk
    int bkr = tid >> 4, bc = (tid & 15) * 4; // B stage
    for (int kt = 0; kt < 125; ++kt) {
        int k0 = kt * 16;
        if (row0 + ar < N_NODES) {
            f32x4 av = *(const f32x4*)(x + (long)(row0 + ar) * KEMB + k0 + ac);
#pragma unroll
            for (int j = 0; j < 4; ++j) As[ar * 17 + ac + j] = av[j];
        } else {
#pragma unroll
            for (int j = 0; j < 4; ++j) As[ar * 17 + ac + j] = 0.f;
        }
        *(f32x4*)(Bs + bkr * 64 + bc) = *(const f32x4*)(W + (long)(k0 + bkr) * EMB + n0 + bc);
        __syncthreads();
#pragma unroll 1
        for (int kk = 0; kk < 16; ++kk) {
            float a[4];
#pragma unroll
            for (int i = 0; i < 4; ++i) a[i] = As[(ty * 4 + i) * 17 + kk];
            f32x4 b = *(const f32x4*)(Bs + kk * 64 + tx * 4);
#pragma unroll
            for (int i = 0; i < 4; ++i)
#pragma unroll
                for (int j = 0; j < 4; ++j) acc[i][j] += a[i] * b[j];
        }
        __syncthreads();
    }
#pragma unroll
    for (int i = 0; i < 4; ++i) {
        int row = row0 + ty * 4 + i;
        if (row >= N_NODES) continue;
        f32x4 o;
#pragma unroll
        for (int j = 0; j < 4; ++j) o[j] = acc[i][j] + bias[n0 + tx * 4 + j];
        *(f32x4*)(h + (long)row * EMB + n0 + tx * 4) = o;
    }
}

// ---------------- fused message f32: m = relu(cat(h[src],ea) @ W + b) * P[idx]; atomic scatter ----------------
__global__ __launch_bounds__(256) void k_msg_f32(const float* __restrict__ h,
                                                 const float* __restrict__ ea,
                                                 const int* __restrict__ src,
                                                 const int* __restrict__ dst,
                                                 const float* __restrict__ mW,   // [160][64]
                                                 const float* __restrict__ mb,   // [64]
                                                 const float* __restrict__ P,    // [2000][64]
                                                 const int* __restrict__ smax,
                                                 float* __restrict__ aggr) {
    int e = blockIdx.x * 256 + threadIdx.x;
    int s = src[e], d = dst[e];
    float acc[PD];
#pragma unroll
    for (int o = 0; o < PD; ++o) acc[o] = mb[o];
#pragma unroll 1
    for (int kb = 0; kb < 10; ++kb) {
        float in[16];
        if (kb < 8) {
            f32x4 v0 = *(const f32x4*)(h + (long)s * EMB + kb * 16);
            f32x4 v1 = *(const f32x4*)(h + (long)s * EMB + kb * 16 + 4);
            f32x4 v2 = *(const f32x4*)(h + (long)s * EMB + kb * 16 + 8);
            f32x4 v3 = *(const f32x4*)(h + (long)s * EMB + kb * 16 + 12);
#pragma unroll
            for (int j = 0; j < 4; ++j) { in[j] = v0[j]; in[4+j] = v1[j]; in[8+j] = v2[j]; in[12+j] = v3[j]; }
        } else {
            f32x4 v0 = *(const f32x4*)(ea + (long)e * ED + (kb - 8) * 16);
            f32x4 v1 = *(const f32x4*)(ea + (long)e * ED + (kb - 8) * 16 + 4);
            f32x4 v2 = *(const f32x4*)(ea + (long)e * ED + (kb - 8) * 16 + 8);
            f32x4 v3 = *(const f32x4*)(ea + (long)e * ED + (kb - 8) * 16 + 12);
#pragma unroll
            for (int j = 0; j < 4; ++j) { in[j] = v0[j]; in[4+j] = v1[j]; in[8+j] = v2[j]; in[12+j] = v3[j]; }
        }
#pragma unroll 1
        for (int kk = 0; kk < 16; ++kk) {
            const float* wrow = mW + (long)(kb * 16 + kk) * PD;  // lane-uniform -> s_load
            float v = in[kk];
#pragma unroll
            for (int o = 0; o < PD; ++o) acc[o] += v * wrow[o];
        }
    }
    int base = *smax - (NGENES - 1);
    const float* Pe = P + (long)(s - base) * PD;
    float* arow = aggr + (long)d * PD;
#pragma unroll
    for (int o = 0; o < PD; ++o) {
        float v = fmaxf(acc[o], 0.f) * Pe[o];
        unsafeAtomicAdd(arow + o, v);
    }
}

// ---------------- update f32 (in-place h): h = relu(cat(aggr,h) @ W + b) ----------------
__global__ __launch_bounds__(256) void k_upd_f32(const float* __restrict__ aggr,
                                                 float* __restrict__ h,
                                                 const float* __restrict__ uW,  // [192][128]
                                                 const float* __restrict__ ub)  // [128]
{
    __shared__ float lds[64 * 193];
    int tid = threadIdx.x;
    int n0 = blockIdx.x * 64;
    for (int i = tid; i < 64 * 64; i += 256) {
        int nl = i >> 6, k = i & 63;
        lds[nl * 193 + k] = (n0 + nl < N_NODES) ? aggr[(long)(n0 + nl) * PD + k] : 0.f;
    }
    for (int i = tid; i < 64 * 128; i += 256) {
        int nl = i >> 7, k = i & 127;
        lds[nl * 193 + 64 + k] = (n0 + nl < N_NODES) ? h[(long)(n0 + nl) * EMB + k] : 0.f;
    }
    __syncthreads();
    int wv = tid >> 6, l = tid & 63;
    int o0 = wv * 32;
    int n = n0 + l;
    float acc[32];
#pragma unroll
    for (int o = 0; o < 32; ++o) acc[o] = ub[o0 + o];
#pragma unroll 1
    for (int k = 0; k < 192; ++k) {
        float v = lds[l * 193 + k];
        const float* wrow = uW + (long)k * EMB + o0;  // lane-uniform -> s_load
#pragma unroll
        for (int o = 0; o < 32; ++o) acc[o] += v * wrow[o];
    }
    if (n < N_NODES) {
#pragma unroll
        for (int c = 0; c < 8; ++c) {
            f32x4 v;
#pragma unroll
            for (int j = 0; j < 4; ++j) v[j] = fmaxf(acc[c * 4 + j], 0.f);
            *(f32x4*)(h + (long)n * EMB + o0 + c * 4) = v;
        }
    }
}

// ---------------- node head f32: out = h @ W_node + b  (f32 output!) ----------------
__global__ __launch_bounds__(256) void k_node_f32(const float* __restrict__ h,
                                                  const float* __restrict__ W,  // [128][16]
                                                  const float* __restrict__ b,
                                                  float* __restrict__ out) {
    int n = blockIdx.x * 256 + threadIdx.x;
    if (n >= N_NODES) return;
    float acc[OUTD];
#pragma unroll
    for (int o = 0; o < OUTD; ++o) acc[o] = b[o];
#pragma unroll 1
    for (int kb = 0; kb < 32; ++kb) {
        f32x4 hv = *(const f32x4*)(h + (long)n * EMB + kb * 4);
#pragma unroll
        for (int j = 0; j < 4; ++j) {
            const float* wrow = W + (long)(kb * 4 + j) * OUTD;  // uniform
#pragma unroll
            for (int o = 0; o < OUTD; ++o) acc[o] += hv[j] * wrow[o];
        }
    }
#pragma unroll
    for (int c = 0; c < 4; ++c) {
        f32x4 v;
#pragma unroll
        for (int j = 0; j < 4; ++j) v[j] = acc[c * 4 + j];
        *(f32x4*)(out + (long)n * OUTD + c * 4) = v;
    }
}

// ---------------- edge head f32: out = dot(cat(h[s],h[d],ea), w) + b  (f32 output!) ----------------
__global__ __launch_bounds__(256) void k_edge_f32(const float* __restrict__ h,
                                                  const float* __restrict__ ea,
                                                  const int* __restrict__ src,
                                                  const int* __restrict__ dst,
                                                  const float* __restrict__ Wep, // [288]
                                                  const float* __restrict__ bep,
                                                  float* __restrict__ out) {
    int e = blockIdx.x * 256 + threadIdx.x;
    int s = src[e], d = dst[e];
    float acc = bep[0];
#pragma unroll 1
    for (int kb = 0; kb < 32; ++kb) {
        f32x4 hv = *(const f32x4*)(h + (long)s * EMB + kb * 4);
#pragma unroll
        for (int j = 0; j < 4; ++j) acc += hv[j] * Wep[kb * 4 + j];
    }
#pragma unroll 1
    for (int kb = 0; kb < 32; ++kb) {
        f32x4 hv = *(const f32x4*)(h + (long)d * EMB + kb * 4);
#pragma unroll
        for (int j = 0; j < 4; ++j) acc += hv[j] * Wep[128 + kb * 4 + j];
    }
#pragma unroll 1
    for (int kb = 0; kb < 8; ++kb) {
        f32x4 av = *(const f32x4*)(ea + (long)e * ED + kb * 4);
#pragma unroll
        for (int j = 0; j < 4; ++j) acc += av[j] * Wep[256 + kb * 4 + j];
    }
    out[e] = acc;
}

extern "C" void kernel_launch(void* const* d_in, const int* in_sizes, int n_in,
                              void* d_out, int out_size, void* d_ws, size_t ws_size,
                              hipStream_t stream) {
    const float* x      = (const float*)d_in[0];
    const float* ea     = (const float*)d_in[1];
    const int*   eidx   = (const int*)d_in[2];
    const float* W_emb  = (const float*)d_in[3];
    const float* b_emb  = (const float*)d_in[4];
    const float* msg_W  = (const float*)d_in[5];
    const float* msg_b  = (const float*)d_in[6];
    const float* upd_W  = (const float*)d_in[7];
    const float* upd_b  = (const float*)d_in[8];
    const float* W_node = (const float*)d_in[9];
    const float* b_node = (const float*)d_in[10];
    const float* W_ep   = (const float*)d_in[11];
    const float* b_ep   = (const float*)d_in[12];
    const float* P      = (const float*)d_in[13];
    float* out = (float*)d_out;   // OUTPUT IS F32 (confirmed by R5 probe)

    const int* src = eidx;
    const int* dst = eidx + NEDGE;

    // ---- workspace: h f32 (10.24 MB) + aggr f32 (5.12 MB) + smax ----
    size_t off = 0;
    char* w = (char*)d_ws;
    float* h    = (float*)(w + off); off += (size_t)N_NODES * EMB * 4;
    float* aggr = (float*)(w + off); off += (size_t)N_NODES * PD * 4;
    int*   smax = (int*)(w + off);   off += 16;
    if (ws_size < off) return;

    hipMemsetAsync(smax, 0, 4, stream);
    k_srcmax<<<NEDGE / 256, 256, 0, stream>>>(src, smax);

    k_emb_f32<<<313 * 2, 256, 0, stream>>>(x, W_emb, b_emb, h);

    // layer 0
    hipMemsetAsync(aggr, 0, (size_t)N_NODES * PD * 4, stream);
    k_msg_f32<<<NEDGE / 256, 256, 0, stream>>>(h, ea, src, dst, msg_W, msg_b, P, smax, aggr);
    k_upd_f32<<<313, 256, 0, stream>>>(aggr, h, upd_W, upd_b);
    // layer 1
    hipMemsetAsync(aggr, 0, (size_t)N_NODES * PD * 4, stream);
    k_msg_f32<<<NEDGE / 256, 256, 0, stream>>>(h, ea, src, dst,
                                               msg_W + 160 * PD, msg_b + PD, P, smax, aggr);
    k_upd_f32<<<313, 256, 0, stream>>>(aggr, h, upd_W + 192 * EMB, upd_b + EMB);

    k_node_f32<<<(N_NODES + 255) / 256, 256, 0, stream>>>(h, W_node, b_node, out);
    k_edge_f32<<<NEDGE / 256, 256, 0, stream>>>(h, ea, src, dst, W_ep, b_ep,
                                                out + (size_t)N_NODES * OUTD);
}